// Round 1
// baseline (4060.642 us; speedup 1.0000x reference)
//
#include <hip/hip_runtime.h>
#include <math.h>

#define Bg 32
#define Ng 2048
#define Kn 20
#define BNn (Bg*Ng)
#define En (BNn*Kn)
#define Hd 64
#define Cd 40

// Build combined first-layer weights:
// wpq[d][l<64]  = W1[d][l] - W1[D+d][l]   (multiplies x_i)
// wpq[d][64+l]  = W1[D+d][l]              (multiplies x_j)
__global__ void prep_w_kernel(const float* __restrict__ w1c, const float* __restrict__ w1d1,
                              const float* __restrict__ w1d2,
                              float* __restrict__ wpq0, float* __restrict__ wpq1,
                              float* __restrict__ wpq2){
  int t = blockIdx.x*256 + threadIdx.x;
  if (t < 3*128){
    int d = t >> 7, l = t & 127;
    wpq0[t] = (l < 64) ? (w1c[d*64 + l] - w1c[(d+3)*64 + l]) : w1c[(d+3)*64 + (l-64)];
  }
  if (t < 64*128){
    int d = t >> 7, l = t & 127;
    wpq1[t] = (l < 64) ? (w1d1[d*64 + l] - w1d1[(d+64)*64 + l]) : w1d1[(d+64)*64 + (l-64)];
    wpq2[t] = (l < 64) ? (w1d2[d*64 + l] - w1d2[(d+64)*64 + l]) : w1d2[(d+64)*64 + (l-64)];
  }
}

__global__ void init_enc_kernel(unsigned int* __restrict__ enc){
  int t = blockIdx.x*256 + threadIdx.x;
  enc[t] = 0x007FFFFFu;   // order-preserving encoding of -inf
}

// X[BN,D] @ wpq[D,128] -> P[BN,64], Q[BN,64]. 8 nodes per block, 128 threads.
template<int D>
__global__ __launch_bounds__(128) void gemm_pq_kernel(const float* __restrict__ x,
                               const float* __restrict__ w,
                               float* __restrict__ P, float* __restrict__ Q){
  __shared__ float xs[8*D];
  int l = threadIdx.x;
  int node0 = blockIdx.x*8;
  float wc[D];
  #pragma unroll
  for (int d=0; d<D; d++) wc[d] = w[d*128 + l];
  for (int i=l; i < 8*D; i += 128) xs[i] = x[(size_t)node0*D + i];
  __syncthreads();
  #pragma unroll
  for (int n=0; n<8; n++){
    float s = 0.f;
    #pragma unroll
    for (int d=0; d<D; d++) s = fmaf(xs[n*D+d], wc[d], s);
    int node = node0 + n;
    if (l < 64) P[(size_t)node*64 + l] = s;
    else        Q[(size_t)node*64 + (l-64)] = s;
  }
}

__global__ __launch_bounds__(256) void sq_kernel(const float* __restrict__ x, float* __restrict__ sq){
  int t = blockIdx.x*256 + threadIdx.x;
  int node = t >> 6, l = t & 63;
  float v = x[(size_t)node*64 + l];
  float s = v*v;
  #pragma unroll
  for (int o=32; o; o>>=1) s += __shfl_xor(s, o, 64);
  if (l == 0) sq[node] = s;
}

// Static EdgeConv: per-edge hidden = relu(P0[dst]+Q0[src]+b1); msg = hidden @ W2;
// atomicMax of order-preserving uint encoding into enc[dst]. b2 deferred to decode.
__global__ __launch_bounds__(256) void edge1_kernel(const int* __restrict__ ei,
        const float* __restrict__ P0, const float* __restrict__ Q0,
        const float* __restrict__ b1, const float* __restrict__ w2,
        unsigned int* __restrict__ enc){
  __shared__ __align__(16) float ts[4][2][Hd];
  int wid = threadIdx.x >> 6, l = threadIdx.x & 63;
  float w2c[Hd];
  #pragma unroll
  for (int d=0; d<Hd; d++) w2c[d] = w2[d*Hd + l];
  float b1l = b1[l];
  int gw = blockIdx.x*4 + wid;
  int nw = gridDim.x*4;               // En % nw == 0 -> equal trip counts for barrier
  int it = 0;
  for (int e = gw; e < En; e += nw, it++){
    int src = ei[e];
    int dst = ei[En + e];
    float t = P0[(size_t)dst*Hd + l] + Q0[(size_t)src*Hd + l] + b1l;
    t = t > 0.f ? t : 0.f;
    int pb = it & 1;
    ts[wid][pb][l] = t;
    __syncthreads();
    float s = 0.f;
    #pragma unroll
    for (int d=0; d<Hd; d+=4){
      float4 tv = *(const float4*)&ts[wid][pb][d];
      s = fmaf(tv.x, w2c[d+0], s);
      s = fmaf(tv.y, w2c[d+1], s);
      s = fmaf(tv.z, w2c[d+2], s);
      s = fmaf(tv.w, w2c[d+3], s);
    }
    unsigned int ue = __float_as_uint(s);
    ue = (ue & 0x80000000u) ? ~ue : (ue | 0x80000000u);
    atomicMax(&enc[(size_t)dst*Hd + l], ue);
  }
}

__global__ __launch_bounds__(256) void decode_elu_kernel(const unsigned int* __restrict__ enc,
         const float* __restrict__ b2, float* __restrict__ x){
  int t = blockIdx.x*256 + threadIdx.x;
  unsigned int e = enc[t];
  unsigned int bits = (e & 0x80000000u) ? (e ^ 0x80000000u) : ~e;
  float f = __uint_as_float(bits);
  if (isfinite(f)) f += b2[t & 63]; else f = 0.f;   // no-edge nodes -> 0 (before bias, like ref)
  x[t] = f > 0.f ? f : expm1f(f);                   // ELU feeding the next dynamic layer
}

// kNN: 1 wave per 64 rows of one graph; lane owns a row. Keys = (double)dist bits + j,
// int64 compare == (dist asc, then j asc) -> identical set to jax.lax.top_k(-d, K).
__global__ __launch_bounds__(64) void knn_kernel(const float* __restrict__ x,
        const float* __restrict__ sq, int* __restrict__ idx){
  int g = blockIdx.x >> 5;
  int row = (blockIdx.x & 31)*64 + threadIdx.x;
  const float* xg = x + (size_t)g*Ng*Hd;
  const float* sg = sq + (size_t)g*Ng;
  float xr[Hd];
  #pragma unroll
  for (int d=0; d<Hd; d+=4){
    float4 v = *(const float4*)(xg + (size_t)row*Hd + d);
    xr[d]=v.x; xr[d+1]=v.y; xr[d+2]=v.z; xr[d+3]=v.w;
  }
  float sr = sg[row];
  long long kb[Kn];
  #pragma unroll
  for (int t=0;t<Kn;t++) kb[t] = 0x7FFFFFFFFFFFFFFFLL;
  for (int j=0; j<Ng; j++){
    const float* xj = xg + (size_t)j*Hd;   // wave-uniform address -> scalar/broadcast loads
    float dot = 0.f;
    #pragma unroll
    for (int d=0; d<Hd; d+=4){
      float4 v = *(const float4*)(xj + d);
      dot = fmaf(xr[d+0], v.x, dot);
      dot = fmaf(xr[d+1], v.y, dot);
      dot = fmaf(xr[d+2], v.z, dot);
      dot = fmaf(xr[d+3], v.w, dot);
    }
    float dist = sr - 2.f*dot + sg[j];
    long long key = __double_as_longlong((double)dist) + (long long)j; // low 29 bits of mantissa are 0; j<2048 fits
    if (__any(key < kb[Kn-1])){
      #pragma unroll
      for (int p=Kn-1; p>0; p--){
        long long ins = (key < kb[p]) ? key : kb[p];
        kb[p] = (key < kb[p-1]) ? kb[p-1] : ins;
      }
      kb[0] = (key < kb[0]) ? key : kb[0];
    }
  }
  int node = g*Ng + row;
  #pragma unroll
  for (int t=0;t<Kn;t++) idx[(size_t)node*Kn + t] = g*Ng + (int)(kb[t] & (Ng-1));
}

// Dynamic EdgeConv second stage: per node, t_k = relu(P_i + Q_j + b1), out = max_k t_k@W2 (+b2, opt ELU)
template<bool ELU>
__global__ __launch_bounds__(64) void dedge_kernel(const float* __restrict__ P, const float* __restrict__ Q,
        const int* __restrict__ idx, const float* __restrict__ b1,
        const float* __restrict__ w2, const float* __restrict__ b2,
        float* __restrict__ out){
  __shared__ __align__(16) float ts[2][Hd];
  int l = threadIdx.x;
  float w2c[Hd];
  #pragma unroll
  for (int d=0; d<Hd; d++) w2c[d] = w2[d*Hd + l];
  float b1l = b1[l], b2l = b2[l];
  for (int i = blockIdx.x; i < BNn; i += gridDim.x){
    float pv = P[(size_t)i*Hd + l] + b1l;
    float acc = -INFINITY;
    for (int k=0; k<Kn; k++){
      int j = idx[(size_t)i*Kn + k];
      float t = pv + Q[(size_t)j*Hd + l];
      t = t > 0.f ? t : 0.f;
      int pb = k & 1;
      ts[pb][l] = t;
      __syncthreads();
      float s = 0.f;
      #pragma unroll
      for (int d=0; d<Hd; d+=4){
        float4 tv = *(const float4*)&ts[pb][d];
        s = fmaf(tv.x, w2c[d+0], s);
        s = fmaf(tv.y, w2c[d+1], s);
        s = fmaf(tv.z, w2c[d+2], s);
        s = fmaf(tv.w, w2c[d+3], s);
      }
      acc = fmaxf(acc, s);
    }
    float o = acc + b2l;
    if (ELU) o = o > 0.f ? o : expm1f(o);
    out[(size_t)i*Hd + l] = o;
  }
}

__global__ __launch_bounds__(64) void final_kernel(const float* __restrict__ h,
        const float* __restrict__ w, const float* __restrict__ bias,
        float* __restrict__ out){
  __shared__ float xs[Hd];
  int c = threadIdx.x;
  float wc[Hd];
  float bc = 0.f;
  if (c < Cd){
    #pragma unroll
    for (int d=0; d<Hd; d++) wc[d] = w[d*Cd + c];
    bc = bias[c];
  }
  for (int i = blockIdx.x; i < BNn; i += gridDim.x){
    __syncthreads();
    xs[c] = h[(size_t)i*Hd + c];
    __syncthreads();
    if (c < Cd){
      float s = bc;
      #pragma unroll
      for (int d=0; d<Hd; d++) s = fmaf(xs[d], wc[d], s);
      out[(size_t)i*Cd + c] = s;
    }
  }
}

extern "C" void kernel_launch(void* const* d_in, const int* in_sizes, int n_in,
                              void* d_out, int out_size, void* d_ws, size_t ws_size,
                              hipStream_t stream){
  const float* x0   = (const float*)d_in[0];
  const int*   ei   = (const int*)d_in[1];
  const float* c1w1 = (const float*)d_in[3];
  const float* c1b1 = (const float*)d_in[4];
  const float* c1w2 = (const float*)d_in[5];
  const float* c1b2 = (const float*)d_in[6];
  const float* d1w1 = (const float*)d_in[7];
  const float* d1b1 = (const float*)d_in[8];
  const float* d1w2 = (const float*)d_in[9];
  const float* d1b2 = (const float*)d_in[10];
  const float* d2w1 = (const float*)d_in[11];
  const float* d2b1 = (const float*)d_in[12];
  const float* d2w2 = (const float*)d_in[13];
  const float* d2b2 = (const float*)d_in[14];
  const float* linw = (const float*)d_in[15];
  const float* linb = (const float*)d_in[16];
  float* out = (float*)d_out;

  char* ws = (char*)d_ws;
  size_t off = 0;
  auto alloc = [&](size_t bytes)->char*{
    char* p = ws + off; off += (bytes + 255) & ~(size_t)255; return p;
  };
  float*        X    = (float*)alloc(sizeof(float)*(size_t)BNn*Hd);
  float*        P    = (float*)alloc(sizeof(float)*(size_t)BNn*Hd);
  float*        Q    = (float*)alloc(sizeof(float)*(size_t)BNn*Hd);
  unsigned int* ENC  = (unsigned int*)alloc(sizeof(unsigned)*(size_t)BNn*Hd);
  float*        SQ   = (float*)alloc(sizeof(float)*BNn);
  int*          IDX  = (int*)alloc(sizeof(int)*(size_t)BNn*Kn);
  float*        WPQ0 = (float*)alloc(sizeof(float)*3*128);
  float*        WPQ1 = (float*)alloc(sizeof(float)*64*128);
  float*        WPQ2 = (float*)alloc(sizeof(float)*64*128);
  (void)ws_size; (void)in_sizes; (void)n_in; (void)out_size;

  prep_w_kernel<<<32, 256, 0, stream>>>(c1w1, d1w1, d2w1, WPQ0, WPQ1, WPQ2);
  init_enc_kernel<<<BNn*Hd/256, 256, 0, stream>>>(ENC);
  gemm_pq_kernel<3><<<BNn/8, 128, 0, stream>>>(x0, WPQ0, P, Q);
  edge1_kernel<<<4096, 256, 0, stream>>>(ei, P, Q, c1b1, c1w2, ENC);
  decode_elu_kernel<<<BNn*Hd/256, 256, 0, stream>>>(ENC, c1b2, X);

  // dynamic layer 1 (writes X in place; dedge reads only P,Q,IDX)
  sq_kernel<<<BNn*Hd/256, 256, 0, stream>>>(X, SQ);
  gemm_pq_kernel<64><<<BNn/8, 128, 0, stream>>>(X, WPQ1, P, Q);
  knn_kernel<<<Bg*32, 64, 0, stream>>>(X, SQ, IDX);
  dedge_kernel<true><<<8192, 64, 0, stream>>>(P, Q, IDX, d1b1, d1w2, d1b2, X);

  // dynamic layer 2 (output -> ENC buffer reused as h2)
  sq_kernel<<<BNn*Hd/256, 256, 0, stream>>>(X, SQ);
  gemm_pq_kernel<64><<<BNn/8, 128, 0, stream>>>(X, WPQ2, P, Q);
  knn_kernel<<<Bg*32, 64, 0, stream>>>(X, SQ, IDX);
  dedge_kernel<false><<<8192, 64, 0, stream>>>(P, Q, IDX, d2b1, d2w2, d2b2, (float*)ENC);

  final_kernel<<<8192, 64, 0, stream>>>((float*)ENC, linw, linb, out);
}